// Round 1
// 2928.050 us; speedup vs baseline: 1.0535x; 1.0535x over previous
//
#include <hip/hip_runtime.h>
#include <cfloat>
#include <cmath>

// B=8 S=32 P=5 C=528 H=784 M=128 N=196 tot=1280 out cols=1697

typedef __attribute__((ext_vector_type(8))) short short8;
typedef __attribute__((ext_vector_type(4))) float f32x4;

__device__ __forceinline__ unsigned bf16r(float f) {
  union { float f; unsigned u; } v;
  v.f = f;
  unsigned u = v.u;
  u += 0x7fffu + ((u >> 16) & 1u);   // round-to-nearest-even
  return u >> 16;
}

__device__ __forceinline__ short8 pack8(const float* f) {
  short8 r;
#pragma unroll
  for (int j = 0; j < 8; ++j) r[j] = (short)bf16r(f[j]);
  return r;
}

__device__ __forceinline__ float tanh_fast(float x) {
  float e = __expf(2.f * x);
  return 1.f - 2.f / (e + 1.f);
}

// ---------------------------------------------------------------------------
// Generic tiled GEMM: C[M,N] = A[M,K] @ Bt[N,K]^T (+bias[N]) — fp32, small use
// ---------------------------------------------------------------------------
#define GT_BM 32
#define GT_BN 64
#define GT_BK 16

__global__ __launch_bounds__(256) void gemm_nt(const float* __restrict__ A,
                                               const float* __restrict__ Bt,
                                               const float* __restrict__ bias,
                                               float* __restrict__ Cm,
                                               int Mn, int Nn, int Kn) {
  __shared__ float sA[GT_BM][GT_BK + 1];
  __shared__ float sB[GT_BK][68];
  const int tid = threadIdx.x;
  const int tm = tid >> 4;
  const int tn = tid & 15;
  const int rowBase = blockIdx.y * GT_BM;
  const int colBase = blockIdx.x * GT_BN;
  float acc[2][4] = {};

  for (int k0 = 0; k0 < Kn; k0 += GT_BK) {
    for (int u = tid; u < GT_BM * GT_BK; u += 256) {
      int r = u >> 4, kk = u & 15;
      int gk = k0 + kk, gr = rowBase + r;
      sA[r][kk] = (gr < Mn && gk < Kn) ? A[(size_t)gr * Kn + gk] : 0.f;
    }
    for (int u = tid; u < GT_BN * GT_BK; u += 256) {
      int n = u >> 4, kk = u & 15;
      int gk = k0 + kk, gn = colBase + n;
      sB[kk][n] = (gn < Nn && gk < Kn) ? Bt[(size_t)gn * Kn + gk] : 0.f;
    }
    __syncthreads();
#pragma unroll
    for (int kk = 0; kk < GT_BK; ++kk) {
      float a0 = sA[tm * 2 + 0][kk];
      float a1 = sA[tm * 2 + 1][kk];
      float b0 = sB[kk][tn * 4 + 0];
      float b1 = sB[kk][tn * 4 + 1];
      float b2 = sB[kk][tn * 4 + 2];
      float b3 = sB[kk][tn * 4 + 3];
      acc[0][0] += a0 * b0; acc[0][1] += a0 * b1; acc[0][2] += a0 * b2; acc[0][3] += a0 * b3;
      acc[1][0] += a1 * b0; acc[1][1] += a1 * b1; acc[1][2] += a1 * b2; acc[1][3] += a1 * b3;
    }
    __syncthreads();
  }
#pragma unroll
  for (int i = 0; i < 2; ++i)
#pragma unroll
    for (int j = 0; j < 4; ++j) {
      int gr = rowBase + tm * 2 + i;
      int gc = colBase + tn * 4 + j;
      if (gr < Mn && gc < Nn) {
        float v = acc[i][j];
        if (bias) v += bias[gc];
        Cm[(size_t)gr * Nn + gc] = v;
      }
    }
}

// ---------------------------------------------------------------------------
// Whh [2352,784] -> WhhT [784,2352]
// ---------------------------------------------------------------------------
__global__ __launch_bounds__(256) void whh_transpose(const float* __restrict__ W,
                                                     float* __restrict__ WT) {
  __shared__ float tile[32][33];
  const int n0 = blockIdx.x * 32;
  const int k0 = blockIdx.y * 32;
  const int tx = threadIdx.x & 31;
  const int ty = threadIdx.x >> 5;
  for (int i = ty; i < 32; i += 8) {
    int n = n0 + i, k = k0 + tx;
    tile[i][tx] = (n < 2352 && k < 784) ? W[(size_t)n * 784 + k] : 0.f;
  }
  __syncthreads();
  for (int i = ty; i < 32; i += 8) {
    int k = k0 + i, n = n0 + tx;
    if (k < 784 && n < 2352) WT[(size_t)k * 2352 + n] = tile[tx][i];
  }
}

// ---------------------------------------------------------------------------
// GRU recurrent dots: gh[b,n] = sum_k h[b,k] * WhhT[k,n], b in [bh*4, bh*4+4)
// grid (37, 2), block 256 = 64 n x 4 b. Coalesced weight reads, LDS h broadcast.
// ---------------------------------------------------------------------------
__global__ __launch_bounds__(256) void gru_dots(const float* __restrict__ WT,
                                                const float* __restrict__ h,
                                                float* __restrict__ gh) {
  __shared__ float sh[4 * 784];
  const int tid = threadIdx.x;
  const int bh = blockIdx.y;
  const int bloc = tid >> 6;
  const int b = bh * 4 + bloc;
  const int n = blockIdx.x * 64 + (tid & 63);
  for (int u = tid; u < 3136; u += 256) sh[u] = h[bh * 3136 + u];
  __syncthreads();
  if (n >= 2352) return;
  const float4* h4 = (const float4*)(sh + bloc * 784);
  const float* wp = WT + n;
  float acc = 0.f;
#pragma unroll 2
  for (int kk = 0; kk < 196; ++kk) {
    float4 hv = h4[kk];
    const float* w = wp + (size_t)(kk * 4) * 2352;
    acc += hv.x * w[0];
    acc += hv.y * w[2352];
    acc += hv.z * w[4704];
    acc += hv.w * w[7056];
  }
  gh[b * 2352 + n] = acc;
}

// ---------------------------------------------------------------------------
// GRU gate combine: h_new from GI row s, gh, bhh. 6272 items.
// ---------------------------------------------------------------------------
__global__ __launch_bounds__(256) void gru_combine(const float* __restrict__ GI,
                                                   const float* __restrict__ gh,
                                                   const float* __restrict__ bhh,
                                                   const float* __restrict__ h_in,
                                                   float* __restrict__ h_out,
                                                   float* __restrict__ pref,
                                                   int s) {
  const int g = blockIdx.x * 256 + threadIdx.x;
  if (g >= 6272) return;
  const int b = g / 784;
  const int j = g - b * 784;
  const int bs = b * 32 + s;
  const float* gi = GI + (size_t)bs * 2352;
  const float* ghb = gh + b * 2352;
  float ghr = ghb[j] + bhh[j];
  float ghz = ghb[784 + j] + bhh[784 + j];
  float ghn = ghb[1568 + j] + bhh[1568 + j];
  float r = 1.f / (1.f + __expf(-(gi[j] + ghr)));
  float z = 1.f / (1.f + __expf(-(gi[784 + j] + ghz)));
  float nn = tanh_fast(gi[1568 + j] + r * ghn);
  float hn = (1.f - z) * nn + z * h_in[g];
  h_out[g] = hn;
  pref[(size_t)bs * 784 + j] = hn;
}

// ---------------------------------------------------------------------------
// Motion BN stats over 256 distinct rows
// ---------------------------------------------------------------------------
__global__ __launch_bounds__(128) void mot_stats(const float* __restrict__ mot,
                                                 float* __restrict__ msum,
                                                 float* __restrict__ msq) {
  int m = threadIdx.x;
  float s = 0.f, q = 0.f;
  for (int r = 0; r < 256; ++r) {
    float v = mot[r * 128 + m];
    s += v;
    q += v * v;
  }
  msum[m] = s;
  msq[m] = q;
}

// ---------------------------------------------------------------------------
// FUSED attention: scores (MFMA) -> softmax -> 1x1 conv (MFMA) -> BN stats.
// One block per t.
// Phase 1 (unchanged from attn_scores_mfma): ssc[n] = Bahdanau score sums.
// Softmax over 196 in LDS (Wpvb dropped: softmax is shift-invariant).
// Phase 2: conv[o,n] = sum_c convw[o,c]*vbase[n*528+c] via mfma 16x16x32:
//   A = convw zero-padded to 16 rows held in registers (aw[17]),
//   B loaded straight from global (bytes just streamed by phase 1 -> L3-hot),
//   C/D: col=lane&15 = n, row=(lane>>4)*4+r = o; q==0 lanes own all 4 o.
//   pre[o,n] = att[n]*conv[o,n] + convb[o]; then BN-stats + vid_pre write.
// Replaces the latency-bound attn_conv (740us: 6-deep shuffle chains, 4.6% HBM).
// ---------------------------------------------------------------------------
struct AttnP1 { short sA[128 * 40]; short sB[224 * 40]; };   // 28160 B
struct AttnP2 { float red[256]; float pre[784]; };           //  4160 B
union AttnU { AttnP1 p1; AttnP2 p2; };

__global__ __launch_bounds__(256, 2) void attn_fused(
    const float* __restrict__ video, const float* __restrict__ Wv,
    const float* __restrict__ Wvb, const float* __restrict__ patt,
    const float* __restrict__ Wpv, const float* __restrict__ convw,
    const float* __restrict__ convb, float* __restrict__ vid_pre,
    float* __restrict__ vstats) {
  __shared__ AttnU u;
  __shared__ float pa[128];
  __shared__ float wpv[128];
  __shared__ float ssc[224];

  const int t = blockIdx.x;
  const int bs = t / 5;
  const int tid = threadIdx.x;
  const int wave = tid >> 6;
  const int lane = tid & 63;
  const int q = lane >> 4;
  const int ln = lane & 15;
  const int wm = wave >> 1;   // 0..1  (m half)
  const int wn = wave & 1;    // 0..1  (n half)

  if (tid < 128) {
    pa[tid] = Wvb[tid] + patt[(size_t)bs * 128 + tid];
    wpv[tid] = Wpv[tid];
  }
  if (tid < 224) ssc[tid] = 0.f;

  f32x4 acc[4][7];
#pragma unroll
  for (int i = 0; i < 4; ++i)
#pragma unroll
    for (int j = 0; j < 7; ++j) acc[i][j] = (f32x4){0.f, 0.f, 0.f, 0.f};

  const float* vbase = video + (size_t)t * 103488;

  for (int c0 = 0; c0 < 544; c0 += 32) {
    // stage A: 128 m x 16 pairs (2 k each)
    for (int uu = tid; uu < 2048; uu += 256) {
      int m = uu >> 4, p = uu & 15;
      int c = c0 + 2 * p;
      float f0 = (c < 528) ? Wv[m * 528 + c] : 0.f;
      float f1 = (c + 1 < 528) ? Wv[m * 528 + c + 1] : 0.f;
      unsigned pack = bf16r(f0) | (bf16r(f1) << 16);
      *(unsigned*)&u.p1.sA[m * 40 + 2 * p] = pack;
    }
    // stage B (transpose + cvt): 224 n x 16 pairs; n fastest for coalescing
    for (int uu = tid; uu < 3584; uu += 256) {
      int p = uu / 224;
      int n = uu - p * 224;
      int c = c0 + 2 * p;
      float f0 = 0.f, f1 = 0.f;
      if (n < 196) {
        if (c < 528) f0 = vbase[(size_t)c * 196 + n];
        if (c + 1 < 528) f1 = vbase[(size_t)(c + 1) * 196 + n];
      }
      unsigned pack = bf16r(f0) | (bf16r(f1) << 16);
      int pc = p ^ ((n & 3) << 2);
      *(unsigned*)&u.p1.sB[n * 40 + 2 * pc] = pack;
    }
    __syncthreads();

    short8 afr[4], bfr[7];
#pragma unroll
    for (int mi = 0; mi < 4; ++mi) {
      int m = wm * 64 + mi * 16 + ln;
      afr[mi] = *(const short8*)&u.p1.sA[m * 40 + q * 8];
    }
#pragma unroll
    for (int nj = 0; nj < 7; ++nj) {
      int n = wn * 112 + nj * 16 + ln;
      int p0 = (q * 4) ^ ((n & 3) << 2);
      bfr[nj] = *(const short8*)&u.p1.sB[n * 40 + 2 * p0];
    }
#pragma unroll
    for (int mi = 0; mi < 4; ++mi)
#pragma unroll
      for (int nj = 0; nj < 7; ++nj)
        acc[mi][nj] = __builtin_amdgcn_mfma_f32_16x16x32_bf16(
            afr[mi], bfr[nj], acc[mi][nj], 0, 0, 0);
    __syncthreads();
  }

  // epilogue: contrib[n] = sum over this lane's 16 m values
  float contrib[7] = {};
#pragma unroll
  for (int mi = 0; mi < 4; ++mi)
#pragma unroll
    for (int r = 0; r < 4; ++r) {
      int m = wm * 64 + mi * 16 + q * 4 + r;
      float w = wpv[m];
      float bia = pa[m];
#pragma unroll
      for (int nj = 0; nj < 7; ++nj)
        contrib[nj] += w * tanh_fast(acc[mi][nj][r] + bia);
    }
#pragma unroll
  for (int nj = 0; nj < 7; ++nj)
    atomicAdd(&ssc[wn * 112 + nj * 16 + ln], contrib[nj]);
  __syncthreads();
  // ---- phase 1 done; p1 LDS region dead from here on ----

  // ---- softmax over ssc[0..195] ----
  float v = (tid < 196) ? ssc[tid] : -FLT_MAX;
  u.p2.red[tid] = v;
  __syncthreads();
  for (int st = 128; st > 0; st >>= 1) {
    if (tid < st) u.p2.red[tid] = fmaxf(u.p2.red[tid], u.p2.red[tid + st]);
    __syncthreads();
  }
  float mx = u.p2.red[0];
  __syncthreads();
  float e = (tid < 196) ? __expf(v - mx) : 0.f;
  u.p2.red[tid] = e;
  __syncthreads();
  for (int st = 128; st > 0; st >>= 1) {
    if (tid < st) u.p2.red[tid] += u.p2.red[tid + st];
    __syncthreads();
  }
  float tot = u.p2.red[0];
  __syncthreads();
  if (tid < 196) ssc[tid] = e / tot;   // ssc now holds att[n]
  __syncthreads();

  // ---- phase 2: 1x1 conv via MFMA on the (196,528) view ----
  short8 aw[17];
#pragma unroll
  for (int k = 0; k < 17; ++k) {
    float fa[8];
#pragma unroll
    for (int j = 0; j < 8; ++j) {
      int c = k * 32 + q * 8 + j;
      fa[j] = (ln < 4 && c < 528) ? convw[ln * 528 + c] : 0.f;
    }
    aw[k] = pack8(fa);
  }

  for (int tile = wave; tile < 13; tile += 4) {
    int n = tile * 16 + ln;
    bool nv = (n < 196);
    const float* vp = vbase + (size_t)n * 528;
    f32x4 cc = (f32x4){0.f, 0.f, 0.f, 0.f};
#pragma unroll
    for (int k = 0; k < 17; ++k) {
      int c0 = k * 32 + q * 8;
      short8 bf;
      if (nv && c0 + 7 < 528) {
        float4 v0 = *(const float4*)(vp + c0);
        float4 v1 = *(const float4*)(vp + c0 + 4);
        float fb[8] = {v0.x, v0.y, v0.z, v0.w, v1.x, v1.y, v1.z, v1.w};
        bf = pack8(fb);
      } else {
        bf = (short8){0, 0, 0, 0, 0, 0, 0, 0};
      }
      cc = __builtin_amdgcn_mfma_f32_16x16x32_bf16(aw[k], bf, cc, 0, 0, 0);
    }
    if (q == 0 && nv) {
      float a = ssc[n];
#pragma unroll
      for (int r = 0; r < 4; ++r)
        u.p2.pre[r * 196 + n] = a * cc[r] + convb[r];
    }
  }
  __syncthreads();

  // ---- BN stats accumulation + vid_pre write ----
  float ls[4] = {0.f, 0.f, 0.f, 0.f};
  float lq[4] = {0.f, 0.f, 0.f, 0.f};
  for (int uu = tid; uu < 784; uu += 256) {
    float x = u.p2.pre[uu];
    vid_pre[(size_t)t * 784 + uu] = x;
    int o = uu / 196;
#pragma unroll
    for (int oo = 0; oo < 4; ++oo) {
      ls[oo] += (o == oo) ? x : 0.f;
      lq[oo] += (o == oo) ? x * x : 0.f;
    }
  }
#pragma unroll
  for (int oo = 0; oo < 4; ++oo)
#pragma unroll
    for (int off = 32; off > 0; off >>= 1) {
      ls[oo] += __shfl_down(ls[oo], off);
      lq[oo] += __shfl_down(lq[oo], off);
    }
  if (lane == 0)
#pragma unroll
    for (int oo = 0; oo < 4; ++oo) {
      atomicAdd(&vstats[oo], ls[oo]);
      atomicAdd(&vstats[4 + oo], lq[oo]);
    }
}

// ---------------------------------------------------------------------------
// Final assembly [1280, 1697]
// ---------------------------------------------------------------------------
__global__ __launch_bounds__(256) void finalize(
    const float* __restrict__ tw, const float* __restrict__ prefb,
    const float* __restrict__ motl, const float* __restrict__ msum,
    const float* __restrict__ msq, const float* __restrict__ mg,
    const float* __restrict__ mb, const float* __restrict__ vid_pre,
    const float* __restrict__ vstats, const float* __restrict__ vg,
    const float* __restrict__ vbb, float* __restrict__ out) {
  int g = blockIdx.x * 256 + threadIdx.x;
  if (g >= 1280 * 1697) return;
  int t = g / 1697;
  int col = g - t * 1697;
  int bs = t / 5;
  int p = t - bs * 5;
  float r;
  if (col == 0) {
    r = tw[p];
  } else if (col < 785) {
    r = prefb[(size_t)bs * 784 + (col - 1)];
  } else if (col < 913) {
    int m = col - 785;
    float x = motl[(size_t)bs * 128 + m];
    float mu = msum[m] * (1.f / 256.f);
    float var = msq[m] * (1.f / 256.f) - mu * mu;
    float y = (x - mu) * rsqrtf(var + 1e-5f) * mg[m] + mb[m];
    r = fmaxf(y, 0.f);
  } else {
    int qd = col - 913;
    int o = qd / 196;
    float x = vid_pre[(size_t)t * 784 + qd];
    float mu = vstats[o] * (1.f / 250880.f);
    float var = vstats[4 + o] * (1.f / 250880.f) - mu * mu;
    float y = (x - mu) * rsqrtf(var + 1e-5f) * vg[o] + vbb[o];
    r = fmaxf(y, 0.f);
  }
  out[g] = r;
}

// ---------------------------------------------------------------------------
extern "C" void kernel_launch(void* const* d_in, const int* in_sizes, int n_in,
                              void* d_out, int out_size, void* d_ws,
                              size_t ws_size, hipStream_t stream) {
  const float* fov = (const float*)d_in[0];
  const float* motion = (const float*)d_in[1];
  const float* video = (const float*)d_in[2];
  const float* timew = (const float*)d_in[3];
  const float* w_ih = (const float*)d_in[4];
  const float* w_hh = (const float*)d_in[5];
  const float* b_ih = (const float*)d_in[6];
  const float* b_hh = (const float*)d_in[7];
  const float* Wp = (const float*)d_in[8];
  const float* Wv_w = (const float*)d_in[9];
  const float* Wv_b = (const float*)d_in[10];
  const float* Wpv_w = (const float*)d_in[11];
  const float* Wpv_b = (const float*)d_in[12];
  const float* conv_w = (const float*)d_in[13];
  const float* conv_b = (const float*)d_in[14];
  const float* vbn_g = (const float*)d_in[15];
  const float* vbn_b = (const float*)d_in[16];
  const float* me_w = (const float*)d_in[17];
  const float* me_b = (const float*)d_in[18];
  const float* mbn_g = (const float*)d_in[19];
  const float* mbn_b = (const float*)d_in[20];
  (void)Wpv_b;  // softmax is shift-invariant: Wpvb contributes nothing downstream

  float* ws = (float*)d_ws;
  float* h0b = ws + 0;             // 6272
  float* stats = ws + 6272;        // 264
  float* msum = stats;
  float* msq = stats + 128;
  float* vstats = stats + 256;
  float* h1b = ws + 6656;          // 6272
  float* gh = ws + 12928;          // 18816
  float* GI = ws + 31744;          // 602112
  float* prefb = ws + 633856;      // 200704
  float* patt = ws + 834560;       // 32768
  float* motl = ws + 867328;       // 32768
  float* vid_pre = ws + 1150976;   // 1003520
  float* WT = ws + 2154496;        // 1843968  (total ~16.0 MB)

  // zero h0 + stats accumulators
  hipMemsetAsync(ws, 0, 6536 * sizeof(float), stream);

  whh_transpose<<<dim3(74, 25), 256, 0, stream>>>(w_hh, WT);

  // GRU input projection: GI[256,2352]
  gemm_nt<<<dim3((2352 + GT_BN - 1) / GT_BN, 256 / GT_BM), 256, 0, stream>>>(
      fov, w_ih, b_ih, GI, 256, 2352, 528);

  for (int s = 0; s < 32; ++s) {
    const float* hin = (s & 1) ? h1b : h0b;
    float* hout = (s & 1) ? h0b : h1b;
    gru_dots<<<dim3(37, 2), 256, 0, stream>>>(WT, hin, gh);
    gru_combine<<<25, 256, 0, stream>>>(GI, gh, b_hh, hin, hout, prefb, s);
  }

  gemm_nt<<<dim3(2, 8), 256, 0, stream>>>(prefb, Wp, nullptr, patt, 256, 128, 784);
  gemm_nt<<<dim3(2, 8), 256, 0, stream>>>(motion, me_w, me_b, motl, 256, 128, 90);
  mot_stats<<<1, 128, 0, stream>>>(motl, msum, msq);

  attn_fused<<<1280, 256, 0, stream>>>(video, Wv_w, Wv_b, patt, Wpv_w, conv_w,
                                       conv_b, vid_pre, vstats);

  int total = 1280 * 1697;
  finalize<<<(total + 255) / 256, 256, 0, stream>>>(
      timew, prefb, motl, msum, msq, mbn_g, mbn_b, vid_pre, vstats, vbn_g,
      vbn_b, (float*)d_out);
}